// Round 1
// baseline (607.209 us; speedup 1.0000x reference)
//
#include <hip/hip_runtime.h>

#define N_NODES 50000
#define N_EDGES 800000
#define D 128
#define BN 8

// Phase 1: edge scatter. 2 edges per 256-thread block; 128 contiguous lanes
// per edge -> coalesced 512B gather of feat row + 512B of fp32 atomics.
__global__ __launch_bounds__(256)
void scatter_kernel(const float* __restrict__ feat,
                    const int* __restrict__ src,
                    const int* __restrict__ dst,
                    float* __restrict__ neigh_sum,   // = d_out, pre-zeroed
                    float* __restrict__ deg,         // in d_ws, pre-zeroed
                    int n_edges) {
    int e = blockIdx.x * 2 + (threadIdx.x >> 7);
    if (e >= n_edges) return;
    int t = threadIdx.x & 127;
    int s = src[e];
    int d = dst[e];
    float v = feat[s * D + t];
    unsafeAtomicAdd(&neigh_sum[d * D + t], v);
    if (t == 0) unsafeAtomicAdd(&deg[d], 1.0f);
}

// Phase 2: per-node finalize. Block = 128 threads handles BN=8 nodes.
// Stage feat rows + degree-normalized neigh rows in LDS (all reads of
// fs[i][k]/hs[i][k] in the k-loop are same-address broadcasts -> conflict
// free). Thread o owns output column o for all 8 nodes; W rows are read
// sequentially per-thread and amortized 8x across nodes (L2-resident: both
// W matrices = 128 KB total, shared by all blocks).
__global__ __launch_bounds__(128)
void finalize_kernel(const float* __restrict__ feat,
                     float* __restrict__ out,        // holds neigh_sum on entry
                     const float* __restrict__ deg,
                     const float* __restrict__ W_self,
                     const float* __restrict__ b_self,
                     const float* __restrict__ W_neigh,
                     const float* __restrict__ bias) {
    __shared__ float fs[BN][D];
    __shared__ float hs[BN][D];
    const int node0 = blockIdx.x * BN;
    const int tid = threadIdx.x;   // 0..127

    #pragma unroll
    for (int i = 0; i < BN; ++i) {
        int n = node0 + i;
        float f = 0.f, h = 0.f;
        if (n < N_NODES) {
            f = feat[n * D + tid];
            float dg = deg[n];
            float scale = dg > 0.f ? 1.0f / dg : 0.f;   // DGL mean: 0 for deg==0
            h = out[n * D + tid] * scale;
        }
        fs[i][tid] = f;
        hs[i][tid] = h;
    }
    __syncthreads();

    const int o = tid;
    float acc[BN];
    #pragma unroll
    for (int i = 0; i < BN; ++i) acc[i] = 0.f;

    const float* __restrict__ ws = &W_self[o * D];
    const float* __restrict__ wn = &W_neigh[o * D];
    #pragma unroll 4
    for (int k = 0; k < D; ++k) {
        float a = ws[k];
        float b = wn[k];
        #pragma unroll
        for (int i = 0; i < BN; ++i)
            acc[i] += fs[i][k] * a + hs[i][k] * b;
    }

    float bb = b_self[o] + bias[o];
    #pragma unroll
    for (int i = 0; i < BN; ++i) {
        int n = node0 + i;
        if (n < N_NODES) out[n * D + o] = acc[i] + bb;
    }
}

extern "C" void kernel_launch(void* const* d_in, const int* in_sizes, int n_in,
                              void* d_out, int out_size, void* d_ws, size_t ws_size,
                              hipStream_t stream) {
    const float* feat    = (const float*)d_in[0];
    const int*   src     = (const int*)d_in[1];
    const int*   dst     = (const int*)d_in[2];
    const float* W_self  = (const float*)d_in[3];
    const float* b_self  = (const float*)d_in[4];
    const float* W_neigh = (const float*)d_in[5];
    const float* bias    = (const float*)d_in[6];
    float* out = (float*)d_out;
    float* deg = (float*)d_ws;
    const int n_edges = in_sizes[1];

    // d_out is the neigh_sum accumulator; ws[0:N_NODES] is degree. Both must
    // be zeroed every call (harness poisons them with 0xAA).
    hipMemsetAsync(out, 0, (size_t)N_NODES * D * sizeof(float), stream);
    hipMemsetAsync(deg, 0, (size_t)N_NODES * sizeof(float), stream);

    dim3 sgrid((n_edges + 1) / 2);
    scatter_kernel<<<sgrid, 256, 0, stream>>>(feat, src, dst, out, deg, n_edges);

    dim3 fgrid((N_NODES + BN - 1) / BN);
    finalize_kernel<<<fgrid, 128, 0, stream>>>(feat, out, deg, W_self, b_self,
                                               W_neigh, bias);
}

// Round 2
// 388.374 us; speedup vs baseline: 1.5635x; 1.5635x over previous
//
#include <hip/hip_runtime.h>

#define N_NODES 50000
#define N_EDGES 800000
#define D 128
#define TN 64   // nodes per finalize block
#define KC 64   // K-chunk

// ws layout (int32 elements):
//   counts  @ 0       [50000]
//   offsets @ 50048   [50001]
//   cursor  @ 100160  [50000]
//   csr_src @ 150272  [800000]
// total ~3.8 MB

__global__ __launch_bounds__(256)
void hist_kernel(const int* __restrict__ dst, int* __restrict__ counts, int n) {
    int e = blockIdx.x * 256 + threadIdx.x;
    if (e < n) atomicAdd(&counts[dst[e]], 1);
}

// Single-block exclusive scan of counts[50000] -> offsets[50001]; cursor = copy.
__global__ __launch_bounds__(1024)
void scan_kernel(const int* __restrict__ counts, int* __restrict__ offsets,
                 int* __restrict__ cursor) {
    const int NT = 1024;
    const int CHUNK = (N_NODES + NT - 1) / NT;  // 49
    __shared__ int partial[NT];
    int t = threadIdx.x;
    int start = t * CHUNK;
    int end = min(start + CHUNK, N_NODES);
    int s = 0;
    for (int i = start; i < end; ++i) s += counts[i];
    partial[t] = s;
    __syncthreads();
    for (int off = 1; off < NT; off <<= 1) {
        int x = (t >= off) ? partial[t - off] : 0;
        __syncthreads();
        partial[t] += x;
        __syncthreads();
    }
    int run = partial[t] - s;  // exclusive prefix
    for (int i = start; i < end; ++i) {
        offsets[i] = run;
        cursor[i]  = run;
        run += counts[i];
    }
    if (t == NT - 1) offsets[N_NODES] = run;
}

__global__ __launch_bounds__(256)
void bin_kernel(const int* __restrict__ src, const int* __restrict__ dst,
                int* __restrict__ cursor, int* __restrict__ csr_src, int n) {
    int e = blockIdx.x * 256 + threadIdx.x;
    if (e < n) {
        int pos = atomicAdd(&cursor[dst[e]], 1);
        csr_src[pos] = src[e];
    }
}

// One wave (64 lanes) per node; lane handles a float2 column pair. Reads
// neighbor rows (coalesced 512B each, feat is L3-resident), no atomics.
// Writes the DEGREE-NORMALIZED h_neigh into d_out (finalize reads it back).
__global__ __launch_bounds__(256)
void aggregate_kernel(const float* __restrict__ feat,
                      const int* __restrict__ offsets,
                      const int* __restrict__ csr_src,
                      float* __restrict__ out) {
    int node = blockIdx.x * 4 + (threadIdx.x >> 6);
    if (node >= N_NODES) return;
    int lane = threadIdx.x & 63;
    int beg = offsets[node], end = offsets[node + 1];
    const float2* f2 = (const float2*)feat;
    float ax = 0.f, ay = 0.f;
    int i = beg;
    for (; i + 1 < end; i += 2) {              // 2x unroll to hide latency
        int s0 = csr_src[i], s1 = csr_src[i + 1];
        float2 v0 = f2[(size_t)s0 * 64 + lane];
        float2 v1 = f2[(size_t)s1 * 64 + lane];
        ax += v0.x; ay += v0.y;
        ax += v1.x; ay += v1.y;
    }
    if (i < end) {
        int s0 = csr_src[i];
        float2 v0 = f2[(size_t)s0 * 64 + lane];
        ax += v0.x; ay += v0.y;
    }
    int dg = end - beg;
    float scale = dg > 0 ? 1.0f / (float)dg : 0.f;  // DGL mean: 0 for deg==0
    float2 r; r.x = ax * scale; r.y = ay * scale;
    ((float2*)out)[(size_t)node * 64 + lane] = r;
}

// out[n][c] = sum_k [feat[n]|h[n]][k] * [W_self|W_neigh][c][k] + b_self[c]+bias[c]
// Block tile: 64 nodes x 128 cols, K=256 in chunks of 64. Thread: 8 nodes x
// 4 cols register block; inner loop is 3 ds_read_b128 + 32 v_fmac per k.
// Each block reads only its own 64 rows of `out` (h part) and writes them
// after the k-loop -> no cross-block hazard.
__global__ __launch_bounds__(256)
void finalize_kernel(const float* __restrict__ feat,
                     float* __restrict__ out,
                     const float* __restrict__ W_self,
                     const float* __restrict__ b_self,
                     const float* __restrict__ W_neigh,
                     const float* __restrict__ bias) {
    __shared__ float As[KC][68];    // [k][node], stride 68: 16B-aligned rows
    __shared__ float Bs[KC][132];   // [k][col],  stride 132: 16B-aligned rows
    const int tid = threadIdx.x;
    const int n0 = blockIdx.x * TN;
    const int r = (tid >> 5) * 8;   // node offset in tile: 0..56
    const int c = (tid & 31) * 4;   // col offset: 0..124

    float acc[8][4];
    #pragma unroll
    for (int i = 0; i < 8; ++i)
        #pragma unroll
        for (int j = 0; j < 4; ++j) acc[i][j] = 0.f;

    const int la_n  = tid >> 2;         // 0..63
    const int la_k0 = (tid & 3) * 16;   // 0,16,32,48
    const int lb_c  = tid >> 1;         // 0..127
    const int lb_k0 = (tid & 1) * 32;   // 0,32

    for (int kc = 0; kc < 2 * D; kc += KC) {
        // A chunk: k<128 -> feat, else h_neigh (currently in `out`)
        {
            const float* srcp = (kc < D)
                ? (feat + (size_t)(n0 + la_n) * D + kc)
                : (out  + (size_t)(n0 + la_n) * D + (kc - D));
            bool ok = (n0 + la_n) < N_NODES;
            #pragma unroll
            for (int j = 0; j < 16; j += 4) {
                float4 v = ok ? *(const float4*)(srcp + la_k0 + j)
                              : make_float4(0.f, 0.f, 0.f, 0.f);
                As[la_k0 + j + 0][la_n] = v.x;
                As[la_k0 + j + 1][la_n] = v.y;
                As[la_k0 + j + 2][la_n] = v.z;
                As[la_k0 + j + 3][la_n] = v.w;
            }
        }
        // B chunk: Bs[kk][col] = W[col][kc+kk]
        {
            const float* wp = (kc < D)
                ? (W_self  + (size_t)lb_c * D + kc)
                : (W_neigh + (size_t)lb_c * D + (kc - D));
            #pragma unroll
            for (int j = 0; j < 32; j += 4) {
                float4 w = *(const float4*)(wp + lb_k0 + j);
                Bs[lb_k0 + j + 0][lb_c] = w.x;
                Bs[lb_k0 + j + 1][lb_c] = w.y;
                Bs[lb_k0 + j + 2][lb_c] = w.z;
                Bs[lb_k0 + j + 3][lb_c] = w.w;
            }
        }
        __syncthreads();
        #pragma unroll 8
        for (int kk = 0; kk < KC; ++kk) {
            float4 b  = *(const float4*)&Bs[kk][c];
            float4 a0 = *(const float4*)&As[kk][r];
            float4 a1 = *(const float4*)&As[kk][r + 4];
            float av[8] = {a0.x, a0.y, a0.z, a0.w, a1.x, a1.y, a1.z, a1.w};
            float bv[4] = {b.x, b.y, b.z, b.w};
            #pragma unroll
            for (int i = 0; i < 8; ++i)
                #pragma unroll
                for (int j = 0; j < 4; ++j)
                    acc[i][j] += av[i] * bv[j];
        }
        __syncthreads();
    }

    float4 bb;
    bb.x = b_self[c + 0] + bias[c + 0];
    bb.y = b_self[c + 1] + bias[c + 1];
    bb.z = b_self[c + 2] + bias[c + 2];
    bb.w = b_self[c + 3] + bias[c + 3];
    #pragma unroll
    for (int i = 0; i < 8; ++i) {
        int n = n0 + r + i;
        if (n < N_NODES) {
            float4 o;
            o.x = acc[i][0] + bb.x; o.y = acc[i][1] + bb.y;
            o.z = acc[i][2] + bb.z; o.w = acc[i][3] + bb.w;
            *(float4*)&out[(size_t)n * D + c] = o;
        }
    }
}

extern "C" void kernel_launch(void* const* d_in, const int* in_sizes, int n_in,
                              void* d_out, int out_size, void* d_ws, size_t ws_size,
                              hipStream_t stream) {
    const float* feat    = (const float*)d_in[0];
    const int*   src     = (const int*)d_in[1];
    const int*   dst     = (const int*)d_in[2];
    const float* W_self  = (const float*)d_in[3];
    const float* b_self  = (const float*)d_in[4];
    const float* W_neigh = (const float*)d_in[5];
    const float* bias    = (const float*)d_in[6];
    float* out = (float*)d_out;
    int*   w   = (int*)d_ws;

    int* counts  = w;
    int* offsets = w + 50048;
    int* cursor  = w + 100160;
    int* csr_src = w + 150272;
    const int n_edges = in_sizes[1];

    hipMemsetAsync(counts, 0, N_NODES * sizeof(int), stream);
    hist_kernel<<<dim3((n_edges + 255) / 256), 256, 0, stream>>>(dst, counts, n_edges);
    scan_kernel<<<dim3(1), 1024, 0, stream>>>(counts, offsets, cursor);
    bin_kernel<<<dim3((n_edges + 255) / 256), 256, 0, stream>>>(src, dst, cursor, csr_src, n_edges);
    aggregate_kernel<<<dim3((N_NODES + 3) / 4), 256, 0, stream>>>(feat, offsets, csr_src, out);
    finalize_kernel<<<dim3((N_NODES + TN - 1) / TN), 256, 0, stream>>>(feat, out, W_self, b_self, W_neigh, bias);
}

// Round 3
// 285.974 us; speedup vs baseline: 2.1233x; 1.3581x over previous
//
#include <hip/hip_runtime.h>

#define N_NODES 50000
#define N_EDGES 800000
#define D 128
#define TN 64   // nodes per finalize block
#define KC 64   // K-chunk
#define SCAN_BLOCKS 25   // 25 blocks * 2048 elems = 51200 >= 50000

// ws layout (int32 elements):
//   counts   @ 0       [50000]
//   offsets  @ 50048   [50001]
//   cursor   @ 100160  [50000]
//   partials @ 150208  [64]
//   csr_src  @ 150272  [800000]

__global__ __launch_bounds__(256)
void hist_kernel(const int* __restrict__ dst, int* __restrict__ counts, int n) {
    int e = blockIdx.x * 256 + threadIdx.x;
    if (e < n) atomicAdd(&counts[dst[e]], 1);
}

// Phase 1 of scan: per-block scan of 2048 counts; local exclusive prefixes
// into offsets; block total into partials[b].
__global__ __launch_bounds__(1024)
void scan1_kernel(const int* __restrict__ counts, int* __restrict__ offsets,
                  int* __restrict__ partials) {
    __shared__ int wsum[16];
    const int tid = threadIdx.x;
    const int lane = tid & 63;
    const int wv = tid >> 6;
    const int i0 = blockIdx.x * 2048 + tid * 2;

    int c0 = 0, c1 = 0;
    if (i0 < N_NODES) {                      // N_NODES even: pair never straddles
        int2 c = ((const int2*)counts)[blockIdx.x * 1024 + tid];
        c0 = c.x; c1 = c.y;
    }
    int s = c0 + c1;

    // inclusive wave scan
    int v = s;
    #pragma unroll
    for (int o = 1; o < 64; o <<= 1) {
        int u = __shfl_up(v, o);
        if (lane >= o) v += u;
    }
    if (lane == 63) wsum[wv] = v;
    __syncthreads();
    if (tid < 16) {
        int x = wsum[tid];
        #pragma unroll
        for (int o = 1; o < 16; o <<= 1) {
            int u = __shfl_up(x, o);
            if (lane >= o) x += u;
        }
        wsum[tid] = x;   // inclusive scan of wave totals
    }
    __syncthreads();
    int wave_off = (wv > 0) ? wsum[wv - 1] : 0;
    int ex = wave_off + (v - s);             // block-local exclusive prefix
    if (i0 < N_NODES) {
        int2 o2; o2.x = ex; o2.y = ex + c0;
        ((int2*)offsets)[blockIdx.x * 1024 + tid] = o2;
    }
    if (tid == 0) partials[blockIdx.x] = wsum[15];
}

// Phase 2: exclusive scan of the 25 block totals (single wave); also writes
// offsets[N_NODES] = total edge count.
__global__ __launch_bounds__(64)
void scan2_kernel(int* __restrict__ partials, int* __restrict__ offsets) {
    int lane = threadIdx.x;
    int v = (lane < SCAN_BLOCKS) ? partials[lane] : 0;
    int orig = v;
    #pragma unroll
    for (int o = 1; o < 32; o <<= 1) {
        int u = __shfl_up(v, o);
        if (lane >= o) v += u;
    }
    if (lane < SCAN_BLOCKS) partials[lane] = v - orig;   // exclusive
    if (lane == SCAN_BLOCKS - 1) offsets[N_NODES] = v;   // grand total
}

// Phase 3: add block prefix; materialize cursor copy.
__global__ __launch_bounds__(1024)
void scan3_kernel(int* __restrict__ offsets, int* __restrict__ cursor,
                  const int* __restrict__ partials) {
    const int tid = threadIdx.x;
    const int i0 = blockIdx.x * 2048 + tid * 2;
    if (i0 >= N_NODES) return;
    int p = partials[blockIdx.x];
    int2 o2 = ((int2*)offsets)[blockIdx.x * 1024 + tid];
    o2.x += p; o2.y += p;
    ((int2*)offsets)[blockIdx.x * 1024 + tid] = o2;
    ((int2*)cursor)[blockIdx.x * 1024 + tid] = o2;
}

__global__ __launch_bounds__(256)
void bin_kernel(const int* __restrict__ src, const int* __restrict__ dst,
                int* __restrict__ cursor, int* __restrict__ csr_src, int n) {
    int e = blockIdx.x * 256 + threadIdx.x;
    if (e < n) {
        int pos = atomicAdd(&cursor[dst[e]], 1);
        csr_src[pos] = src[e];
    }
}

// Half-wave (32 lanes) per node, float4 per lane: each neighbor-row read is
// one global_load_dwordx4 x 32 lanes = 512B. 8 nodes per 256-thread block.
__global__ __launch_bounds__(256)
void aggregate_kernel(const float* __restrict__ feat,
                      const int* __restrict__ offsets,
                      const int* __restrict__ csr_src,
                      float* __restrict__ out) {
    int node = blockIdx.x * 8 + (threadIdx.x >> 5);
    if (node >= N_NODES) return;
    int lane = threadIdx.x & 31;
    int beg = offsets[node], end = offsets[node + 1];
    const float4* f4 = (const float4*)feat;
    float ax = 0.f, ay = 0.f, az = 0.f, aw = 0.f;
    int i = beg;
    for (; i + 1 < end; i += 2) {
        int s0 = csr_src[i], s1 = csr_src[i + 1];
        float4 v0 = f4[(size_t)s0 * 32 + lane];
        float4 v1 = f4[(size_t)s1 * 32 + lane];
        ax += v0.x; ay += v0.y; az += v0.z; aw += v0.w;
        ax += v1.x; ay += v1.y; az += v1.z; aw += v1.w;
    }
    if (i < end) {
        float4 v0 = f4[(size_t)csr_src[i] * 32 + lane];
        ax += v0.x; ay += v0.y; az += v0.z; aw += v0.w;
    }
    int dg = end - beg;
    float scale = dg > 0 ? 1.0f / (float)dg : 0.f;   // DGL mean: 0 for deg==0
    float4 r; r.x = ax * scale; r.y = ay * scale; r.z = az * scale; r.w = aw * scale;
    ((float4*)out)[(size_t)node * 32 + lane] = r;
}

// 64 nodes x 128 cols tile, K=256 ([feat|h] vs [W_self|W_neigh]); 8x4
// register block per thread. Each block only touches its own 64 out-rows.
__global__ __launch_bounds__(256)
void finalize_kernel(const float* __restrict__ feat,
                     float* __restrict__ out,
                     const float* __restrict__ W_self,
                     const float* __restrict__ b_self,
                     const float* __restrict__ W_neigh,
                     const float* __restrict__ bias) {
    __shared__ float As[KC][68];
    __shared__ float Bs[KC][132];
    const int tid = threadIdx.x;
    const int n0 = blockIdx.x * TN;
    const int r = (tid >> 5) * 8;
    const int c = (tid & 31) * 4;

    float acc[8][4];
    #pragma unroll
    for (int i = 0; i < 8; ++i)
        #pragma unroll
        for (int j = 0; j < 4; ++j) acc[i][j] = 0.f;

    const int la_n  = tid >> 2;
    const int la_k0 = (tid & 3) * 16;
    const int lb_c  = tid >> 1;
    const int lb_k0 = (tid & 1) * 32;

    for (int kc = 0; kc < 2 * D; kc += KC) {
        {
            const float* srcp = (kc < D)
                ? (feat + (size_t)(n0 + la_n) * D + kc)
                : (out  + (size_t)(n0 + la_n) * D + (kc - D));
            bool ok = (n0 + la_n) < N_NODES;
            #pragma unroll
            for (int j = 0; j < 16; j += 4) {
                float4 v = ok ? *(const float4*)(srcp + la_k0 + j)
                              : make_float4(0.f, 0.f, 0.f, 0.f);
                As[la_k0 + j + 0][la_n] = v.x;
                As[la_k0 + j + 1][la_n] = v.y;
                As[la_k0 + j + 2][la_n] = v.z;
                As[la_k0 + j + 3][la_n] = v.w;
            }
        }
        {
            const float* wp = (kc < D)
                ? (W_self  + (size_t)lb_c * D + kc)
                : (W_neigh + (size_t)lb_c * D + (kc - D));
            #pragma unroll
            for (int j = 0; j < 32; j += 4) {
                float4 w = *(const float4*)(wp + lb_k0 + j);
                Bs[lb_k0 + j + 0][lb_c] = w.x;
                Bs[lb_k0 + j + 1][lb_c] = w.y;
                Bs[lb_k0 + j + 2][lb_c] = w.z;
                Bs[lb_k0 + j + 3][lb_c] = w.w;
            }
        }
        __syncthreads();
        #pragma unroll 8
        for (int kk = 0; kk < KC; ++kk) {
            float4 b  = *(const float4*)&Bs[kk][c];
            float4 a0 = *(const float4*)&As[kk][r];
            float4 a1 = *(const float4*)&As[kk][r + 4];
            float av[8] = {a0.x, a0.y, a0.z, a0.w, a1.x, a1.y, a1.z, a1.w};
            float bv[4] = {b.x, b.y, b.z, b.w};
            #pragma unroll
            for (int i = 0; i < 8; ++i)
                #pragma unroll
                for (int j = 0; j < 4; ++j)
                    acc[i][j] += av[i] * bv[j];
        }
        __syncthreads();
    }

    float4 bb;
    bb.x = b_self[c + 0] + bias[c + 0];
    bb.y = b_self[c + 1] + bias[c + 1];
    bb.z = b_self[c + 2] + bias[c + 2];
    bb.w = b_self[c + 3] + bias[c + 3];
    #pragma unroll
    for (int i = 0; i < 8; ++i) {
        int n = n0 + r + i;
        if (n < N_NODES) {
            float4 o;
            o.x = acc[i][0] + bb.x; o.y = acc[i][1] + bb.y;
            o.z = acc[i][2] + bb.z; o.w = acc[i][3] + bb.w;
            *(float4*)&out[(size_t)n * D + c] = o;
        }
    }
}

extern "C" void kernel_launch(void* const* d_in, const int* in_sizes, int n_in,
                              void* d_out, int out_size, void* d_ws, size_t ws_size,
                              hipStream_t stream) {
    const float* feat    = (const float*)d_in[0];
    const int*   src     = (const int*)d_in[1];
    const int*   dst     = (const int*)d_in[2];
    const float* W_self  = (const float*)d_in[3];
    const float* b_self  = (const float*)d_in[4];
    const float* W_neigh = (const float*)d_in[5];
    const float* bias    = (const float*)d_in[6];
    float* out = (float*)d_out;
    int*   w   = (int*)d_ws;

    int* counts   = w;
    int* offsets  = w + 50048;
    int* cursor   = w + 100160;
    int* partials = w + 150208;
    int* csr_src  = w + 150272;
    const int n_edges = in_sizes[1];

    hipMemsetAsync(counts, 0, N_NODES * sizeof(int), stream);
    hist_kernel<<<dim3((n_edges + 255) / 256), 256, 0, stream>>>(dst, counts, n_edges);
    scan1_kernel<<<dim3(SCAN_BLOCKS), 1024, 0, stream>>>(counts, offsets, partials);
    scan2_kernel<<<dim3(1), 64, 0, stream>>>(partials, offsets);
    scan3_kernel<<<dim3(SCAN_BLOCKS), 1024, 0, stream>>>(offsets, cursor, partials);
    bin_kernel<<<dim3((n_edges + 255) / 256), 256, 0, stream>>>(src, dst, cursor, csr_src, n_edges);
    aggregate_kernel<<<dim3((N_NODES + 7) / 8), 256, 0, stream>>>(feat, offsets, csr_src, out);
    finalize_kernel<<<dim3((N_NODES + TN - 1) / TN), 256, 0, stream>>>(feat, out, W_self, b_self, W_neigh, bias);
}

// Round 4
// 256.397 us; speedup vs baseline: 2.3682x; 1.1154x over previous
//
#include <hip/hip_runtime.h>

#define N_NODES 50000
#define N_EDGES 800000
#define D 128
#define TN 64
#define KC 64
#define SCAN_BLOCKS 25

typedef __bf16 bf16x8 __attribute__((ext_vector_type(8)));
typedef __bf16 bf16x4 __attribute__((ext_vector_type(4)));
typedef float  f32x4  __attribute__((ext_vector_type(4)));

// ws layout:
//   ints:  counts @0 [50000] | offsets @50048 [50001] | cursor @100160 [50000]
//          partials @150208 [64] | csr_src @150272 [800000]   (end byte 3,801,088)
//   fast-path extras (bytes):
//          g16  @ 3,801,088  [12,800,000]
//          Ws16 @16,601,088  [32,768]
//          Wn16 @16,633,856  [32,768]
//          biasc@16,666,624  [512]        total 16,667,136
#define G16_OFF   3801088ull
#define WS16_OFF 16601088ull
#define WN16_OFF 16633856ull
#define BIAS_OFF 16666624ull
#define WS_NEED  16667136ull

__global__ __launch_bounds__(256)
void hist_kernel(const int* __restrict__ dst, int* __restrict__ counts, int n) {
    int e = blockIdx.x * 256 + threadIdx.x;
    if (e < n) atomicAdd(&counts[dst[e]], 1);
}

__global__ __launch_bounds__(1024)
void scan1_kernel(const int* __restrict__ counts, int* __restrict__ offsets,
                  int* __restrict__ partials) {
    __shared__ int wsum[16];
    const int tid = threadIdx.x;
    const int lane = tid & 63;
    const int wv = tid >> 6;
    const int i0 = blockIdx.x * 2048 + tid * 2;
    int c0 = 0, c1 = 0;
    if (i0 < N_NODES) {
        int2 c = ((const int2*)counts)[blockIdx.x * 1024 + tid];
        c0 = c.x; c1 = c.y;
    }
    int s = c0 + c1;
    int v = s;
    #pragma unroll
    for (int o = 1; o < 64; o <<= 1) {
        int u = __shfl_up(v, o);
        if (lane >= o) v += u;
    }
    if (lane == 63) wsum[wv] = v;
    __syncthreads();
    if (tid < 16) {
        int x = wsum[tid];
        #pragma unroll
        for (int o = 1; o < 16; o <<= 1) {
            int u = __shfl_up(x, o);
            if (lane >= o) x += u;
        }
        wsum[tid] = x;
    }
    __syncthreads();
    int wave_off = (wv > 0) ? wsum[wv - 1] : 0;
    int ex = wave_off + (v - s);
    if (i0 < N_NODES) {
        int2 o2; o2.x = ex; o2.y = ex + c0;
        ((int2*)offsets)[blockIdx.x * 1024 + tid] = o2;
    }
    if (tid == 0) partials[blockIdx.x] = wsum[15];
}

__global__ __launch_bounds__(64)
void scan2_kernel(int* __restrict__ partials, int* __restrict__ offsets) {
    int lane = threadIdx.x;
    int v = (lane < SCAN_BLOCKS) ? partials[lane] : 0;
    int orig = v;
    #pragma unroll
    for (int o = 1; o < 32; o <<= 1) {
        int u = __shfl_up(v, o);
        if (lane >= o) v += u;
    }
    if (lane < SCAN_BLOCKS) partials[lane] = v - orig;
    if (lane == SCAN_BLOCKS - 1) offsets[N_NODES] = v;
}

__global__ __launch_bounds__(1024)
void scan3_kernel(int* __restrict__ offsets, int* __restrict__ cursor,
                  const int* __restrict__ partials) {
    const int tid = threadIdx.x;
    const int i0 = blockIdx.x * 2048 + tid * 2;
    if (i0 >= N_NODES) return;
    int p = partials[blockIdx.x];
    int2 o2 = ((int2*)offsets)[blockIdx.x * 1024 + tid];
    o2.x += p; o2.y += p;
    ((int2*)offsets)[blockIdx.x * 1024 + tid] = o2;
    ((int2*)cursor)[blockIdx.x * 1024 + tid] = o2;
}

__global__ __launch_bounds__(256)
void bin_kernel(const int* __restrict__ src, const int* __restrict__ dst,
                int* __restrict__ cursor, int* __restrict__ csr_src, int n) {
    int e = blockIdx.x * 256 + threadIdx.x;
    if (e < n) {
        int pos = atomicAdd(&cursor[dst[e]], 1);
        csr_src[pos] = src[e];
    }
}

// ---- fast path -------------------------------------------------------------

__global__ __launch_bounds__(256)
void convert_w_kernel(const float* __restrict__ Ws, const float* __restrict__ Wn,
                      const float* __restrict__ b_self, const float* __restrict__ bias,
                      __bf16* __restrict__ Ws16, __bf16* __restrict__ Wn16,
                      float* __restrict__ bias_comb) {
    if (blockIdx.x < 16) {
        int i = (blockIdx.x * 256 + threadIdx.x) * 4;   // < 16384
        float4 a = *(const float4*)(Ws + i);
        float4 b = *(const float4*)(Wn + i);
        bf16x4 s, n;
        s[0]=(__bf16)a.x; s[1]=(__bf16)a.y; s[2]=(__bf16)a.z; s[3]=(__bf16)a.w;
        n[0]=(__bf16)b.x; n[1]=(__bf16)b.y; n[2]=(__bf16)b.z; n[3]=(__bf16)b.w;
        *(bf16x4*)(Ws16 + i) = s;
        *(bf16x4*)(Wn16 + i) = n;
    } else if (threadIdx.x < D) {
        bias_comb[threadIdx.x] = b_self[threadIdx.x] + bias[threadIdx.x];
    }
}

// Block = 256 (4 waves) covers 32 nodes x 128 cols for BOTH mats.
// Wave w: cols [w*32, w*32+32). MFMA 16x16x32 bf16, fp32 accum.
// A-frag: lane holds feat[r0 + (lane&15)][k0 + (lane>>4)*8 + j], j=0..7.
// B-frag: lane holds W[c0 + (lane&15)][k0 + (lane>>4)*8 + j]  (B[k][n] = W[n][k]).
// D: col = c0 + (lane&15), row = r0 + (lane>>4)*4 + reg.
__global__ __launch_bounds__(256)
void gemm_kernel(const float* __restrict__ feat,
                 const __bf16* __restrict__ Ws16,
                 const __bf16* __restrict__ Wn16,
                 const float* __restrict__ bias_comb,
                 float* __restrict__ out,
                 __bf16* __restrict__ g16) {
    const int tid  = threadIdx.x;
    const int wv   = tid >> 6;
    const int lane = tid & 63;
    const int m    = lane & 15;
    const int quad = lane >> 4;
    const int n0   = blockIdx.x * 32;
    const int kb   = quad * 8;

    f32x4 accS[2][2] = {};   // [row-tile][col-tile]
    f32x4 accN[2][2] = {};

    #pragma unroll
    for (int k0 = 0; k0 < D; k0 += 32) {
        const int kbase = k0 + kb;
        bf16x8 a[2];
        #pragma unroll
        for (int rt = 0; rt < 2; ++rt) {
            int row = n0 + rt * 16 + m;
            row = row < N_NODES ? row : N_NODES - 1;   // clamp: loads only
            const float* p = feat + (size_t)row * D + kbase;
            float4 f0 = *(const float4*)p;
            float4 f1 = *(const float4*)(p + 4);
            bf16x8 t;
            t[0]=(__bf16)f0.x; t[1]=(__bf16)f0.y; t[2]=(__bf16)f0.z; t[3]=(__bf16)f0.w;
            t[4]=(__bf16)f1.x; t[5]=(__bf16)f1.y; t[6]=(__bf16)f1.z; t[7]=(__bf16)f1.w;
            a[rt] = t;
        }
        #pragma unroll
        for (int ct = 0; ct < 2; ++ct) {
            int col = wv * 32 + ct * 16 + m;
            bf16x8 bs = *(const bf16x8*)(Ws16 + (size_t)col * D + kbase);
            bf16x8 bn = *(const bf16x8*)(Wn16 + (size_t)col * D + kbase);
            #pragma unroll
            for (int rt = 0; rt < 2; ++rt) {
                accS[rt][ct] = __builtin_amdgcn_mfma_f32_16x16x32_bf16(a[rt], bs, accS[rt][ct], 0, 0, 0);
                accN[rt][ct] = __builtin_amdgcn_mfma_f32_16x16x32_bf16(a[rt], bn, accN[rt][ct], 0, 0, 0);
            }
        }
    }

    #pragma unroll
    for (int ct = 0; ct < 2; ++ct) {
        int col = wv * 32 + ct * 16 + m;
        float bb = bias_comb[col];
        #pragma unroll
        for (int rt = 0; rt < 2; ++rt) {
            #pragma unroll
            for (int r = 0; r < 4; ++r) {
                int node = n0 + rt * 16 + quad * 4 + r;
                if (node < N_NODES) {
                    out[(size_t)node * D + col] = accS[rt][ct][r] + bb;
                    g16[(size_t)node * D + col] = (__bf16)accN[rt][ct][r];
                }
            }
        }
    }
}

__device__ __forceinline__ float bf2f(unsigned short u) {
    union { unsigned int i; float f; } c;
    c.i = (unsigned int)u << 16;
    return c.f;
}

// Half-wave per node: gather bf16 g-rows (256B each), fp32 accumulate,
// add mean into out (which already holds the self part + bias).
__global__ __launch_bounds__(256)
void aggregate_g_kernel(const __bf16* __restrict__ g16,
                        const int* __restrict__ offsets,
                        const int* __restrict__ csr_src,
                        float* __restrict__ out) {
    int node = blockIdx.x * 8 + (threadIdx.x >> 5);
    if (node >= N_NODES) return;
    int lane = threadIdx.x & 31;
    int beg = offsets[node], end = offsets[node + 1];
    const unsigned short* g = (const unsigned short*)g16;
    float a0 = 0.f, a1 = 0.f, a2 = 0.f, a3 = 0.f;
    int i = beg;
    for (; i + 1 < end; i += 2) {
        int s0 = csr_src[i], s1 = csr_src[i + 1];
        ushort4 u0 = *(const ushort4*)(g + (size_t)s0 * D + lane * 4);
        ushort4 u1 = *(const ushort4*)(g + (size_t)s1 * D + lane * 4);
        a0 += bf2f(u0.x) + bf2f(u1.x);
        a1 += bf2f(u0.y) + bf2f(u1.y);
        a2 += bf2f(u0.z) + bf2f(u1.z);
        a3 += bf2f(u0.w) + bf2f(u1.w);
    }
    if (i < end) {
        ushort4 u0 = *(const ushort4*)(g + (size_t)csr_src[i] * D + lane * 4);
        a0 += bf2f(u0.x); a1 += bf2f(u0.y); a2 += bf2f(u0.z); a3 += bf2f(u0.w);
    }
    int dg = end - beg;
    float sc = dg > 0 ? 1.0f / (float)dg : 0.f;   // DGL mean: 0 for deg==0
    float4 o = *(float4*)(out + (size_t)node * D + lane * 4);
    o.x += a0 * sc; o.y += a1 * sc; o.z += a2 * sc; o.w += a3 * sc;
    *(float4*)(out + (size_t)node * D + lane * 4) = o;
}

// ---- fallback path (round-3 kernels, used only if ws is too small) ---------

__global__ __launch_bounds__(256)
void aggregate_kernel(const float* __restrict__ feat,
                      const int* __restrict__ offsets,
                      const int* __restrict__ csr_src,
                      float* __restrict__ out) {
    int node = blockIdx.x * 8 + (threadIdx.x >> 5);
    if (node >= N_NODES) return;
    int lane = threadIdx.x & 31;
    int beg = offsets[node], end = offsets[node + 1];
    const float4* f4 = (const float4*)feat;
    float ax = 0.f, ay = 0.f, az = 0.f, aw = 0.f;
    int i = beg;
    for (; i + 1 < end; i += 2) {
        int s0 = csr_src[i], s1 = csr_src[i + 1];
        float4 v0 = f4[(size_t)s0 * 32 + lane];
        float4 v1 = f4[(size_t)s1 * 32 + lane];
        ax += v0.x; ay += v0.y; az += v0.z; aw += v0.w;
        ax += v1.x; ay += v1.y; az += v1.z; aw += v1.w;
    }
    if (i < end) {
        float4 v0 = f4[(size_t)csr_src[i] * 32 + lane];
        ax += v0.x; ay += v0.y; az += v0.z; aw += v0.w;
    }
    int dg = end - beg;
    float scale = dg > 0 ? 1.0f / (float)dg : 0.f;
    float4 r; r.x = ax * scale; r.y = ay * scale; r.z = az * scale; r.w = aw * scale;
    ((float4*)out)[(size_t)node * 32 + lane] = r;
}

__global__ __launch_bounds__(256)
void finalize_kernel(const float* __restrict__ feat,
                     float* __restrict__ out,
                     const float* __restrict__ W_self,
                     const float* __restrict__ b_self,
                     const float* __restrict__ W_neigh,
                     const float* __restrict__ bias) {
    __shared__ float As[KC][68];
    __shared__ float Bs[KC][132];
    const int tid = threadIdx.x;
    const int n0 = blockIdx.x * TN;
    const int r = (tid >> 5) * 8;
    const int c = (tid & 31) * 4;
    float acc[8][4];
    #pragma unroll
    for (int i = 0; i < 8; ++i)
        #pragma unroll
        for (int j = 0; j < 4; ++j) acc[i][j] = 0.f;
    const int la_n  = tid >> 2;
    const int la_k0 = (tid & 3) * 16;
    const int lb_c  = tid >> 1;
    const int lb_k0 = (tid & 1) * 32;
    for (int kc = 0; kc < 2 * D; kc += KC) {
        {
            const float* srcp = (kc < D)
                ? (feat + (size_t)(n0 + la_n) * D + kc)
                : (out  + (size_t)(n0 + la_n) * D + (kc - D));
            bool ok = (n0 + la_n) < N_NODES;
            #pragma unroll
            for (int j = 0; j < 16; j += 4) {
                float4 v = ok ? *(const float4*)(srcp + la_k0 + j)
                              : make_float4(0.f, 0.f, 0.f, 0.f);
                As[la_k0 + j + 0][la_n] = v.x;
                As[la_k0 + j + 1][la_n] = v.y;
                As[la_k0 + j + 2][la_n] = v.z;
                As[la_k0 + j + 3][la_n] = v.w;
            }
        }
        {
            const float* wp = (kc < D)
                ? (W_self  + (size_t)lb_c * D + kc)
                : (W_neigh + (size_t)lb_c * D + (kc - D));
            #pragma unroll
            for (int j = 0; j < 32; j += 4) {
                float4 w = *(const float4*)(wp + lb_k0 + j);
                Bs[lb_k0 + j + 0][lb_c] = w.x;
                Bs[lb_k0 + j + 1][lb_c] = w.y;
                Bs[lb_k0 + j + 2][lb_c] = w.z;
                Bs[lb_k0 + j + 3][lb_c] = w.w;
            }
        }
        __syncthreads();
        #pragma unroll 8
        for (int kk = 0; kk < KC; ++kk) {
            float4 b  = *(const float4*)&Bs[kk][c];
            float4 a0 = *(const float4*)&As[kk][r];
            float4 a1 = *(const float4*)&As[kk][r + 4];
            float av[8] = {a0.x, a0.y, a0.z, a0.w, a1.x, a1.y, a1.z, a1.w};
            float bv[4] = {b.x, b.y, b.z, b.w};
            #pragma unroll
            for (int i = 0; i < 8; ++i)
                #pragma unroll
                for (int j = 0; j < 4; ++j)
                    acc[i][j] += av[i] * bv[j];
        }
        __syncthreads();
    }
    float4 bb;
    bb.x = b_self[c + 0] + bias[c + 0];
    bb.y = b_self[c + 1] + bias[c + 1];
    bb.z = b_self[c + 2] + bias[c + 2];
    bb.w = b_self[c + 3] + bias[c + 3];
    #pragma unroll
    for (int i = 0; i < 8; ++i) {
        int n = n0 + r + i;
        if (n < N_NODES) {
            float4 o;
            o.x = acc[i][0] + bb.x; o.y = acc[i][1] + bb.y;
            o.z = acc[i][2] + bb.z; o.w = acc[i][3] + bb.w;
            *(float4*)&out[(size_t)n * D + c] = o;
        }
    }
}

extern "C" void kernel_launch(void* const* d_in, const int* in_sizes, int n_in,
                              void* d_out, int out_size, void* d_ws, size_t ws_size,
                              hipStream_t stream) {
    const float* feat    = (const float*)d_in[0];
    const int*   src     = (const int*)d_in[1];
    const int*   dst     = (const int*)d_in[2];
    const float* W_self  = (const float*)d_in[3];
    const float* b_self  = (const float*)d_in[4];
    const float* W_neigh = (const float*)d_in[5];
    const float* bias    = (const float*)d_in[6];
    float* out = (float*)d_out;
    int*   w   = (int*)d_ws;

    int* counts   = w;
    int* offsets  = w + 50048;
    int* cursor   = w + 100160;
    int* partials = w + 150208;
    int* csr_src  = w + 150272;
    const int n_edges = in_sizes[1];

    hipMemsetAsync(counts, 0, N_NODES * sizeof(int), stream);
    hist_kernel<<<dim3((n_edges + 255) / 256), 256, 0, stream>>>(dst, counts, n_edges);
    scan1_kernel<<<dim3(SCAN_BLOCKS), 1024, 0, stream>>>(counts, offsets, partials);
    scan2_kernel<<<dim3(1), 64, 0, stream>>>(partials, offsets);
    scan3_kernel<<<dim3(SCAN_BLOCKS), 1024, 0, stream>>>(offsets, cursor, partials);
    bin_kernel<<<dim3((n_edges + 255) / 256), 256, 0, stream>>>(src, dst, cursor, csr_src, n_edges);

    if (ws_size >= WS_NEED) {
        __bf16* g16   = (__bf16*)((char*)d_ws + G16_OFF);
        __bf16* Ws16  = (__bf16*)((char*)d_ws + WS16_OFF);
        __bf16* Wn16  = (__bf16*)((char*)d_ws + WN16_OFF);
        float*  biasc = (float*)((char*)d_ws + BIAS_OFF);
        convert_w_kernel<<<dim3(17), 256, 0, stream>>>(W_self, W_neigh, b_self, bias,
                                                       Ws16, Wn16, biasc);
        gemm_kernel<<<dim3((N_NODES + 31) / 32), 256, 0, stream>>>(feat, Ws16, Wn16,
                                                                   biasc, out, g16);
        aggregate_g_kernel<<<dim3((N_NODES + 7) / 8), 256, 0, stream>>>(g16, offsets,
                                                                        csr_src, out);
    } else {
        aggregate_kernel<<<dim3((N_NODES + 7) / 8), 256, 0, stream>>>(feat, offsets,
                                                                      csr_src, out);
        finalize_kernel<<<dim3((N_NODES + TN - 1) / TN), 256, 0, stream>>>(feat, out,
                                                        W_self, b_self, W_neigh, bias);
    }
}

// Round 5
// 201.117 us; speedup vs baseline: 3.0192x; 1.2749x over previous
//
#include <hip/hip_runtime.h>

#define N_NODES 50000
#define N_EDGES 800000
#define D 128
#define NBUK 196        // ceil(50000/256) buckets of 256 nodes
#define PCHUNK 3200     // edges per partition block
#define PBLOCKS 250     // 250*3200 = 800000

typedef __bf16 bf16x8 __attribute__((ext_vector_type(8)));
typedef __bf16 bf16x4 __attribute__((ext_vector_type(4)));
typedef float  f32x4  __attribute__((ext_vector_type(4)));

// ws layout (bytes):
//   offsets      @ 0         [50001 i32]   -> 200,004  (pad to 200,192)
//   bucket_total @ 200,192   [256 i32]     (memset 1KB each call)
//   gcursor      @ 201,216   [256 i32]
//   bucket_base  @ 202,240   [260 i32]     -> 203,280 (pad to 203,776)
//   csr_src      @ 203,776   [800000 i32]  -> 3,403,776
//   packed       @ 3,403,776 [800000 i32]  -> 6,603,776
//   g16          @ 3,403,776 [6,400,000 bf16] (OVERLAYS packed: packed is dead
//                                             before gemm writes g16) -> 16,203,776
//   Ws16         @ 16,203,776 [32768 B]
//   Wn16         @ 16,236,544 [32768 B]
//   biasc        @ 16,269,312 [512 B]      total 16,269,824 (< proven 16.67MB)
#define OFF_OFFSETS   0ull
#define OFF_BTOTAL    200192ull
#define OFF_GCURSOR   201216ull
#define OFF_BBASE     202240ull
#define OFF_CSR       203776ull
#define OFF_PACKED    3403776ull
#define OFF_G16       3403776ull
#define OFF_WS16      16203776ull
#define OFF_WN16      16236544ull
#define OFF_BIASC     16269312ull

// ---- CSR build: two-level LDS-staged radix partition -----------------------

__global__ __launch_bounds__(256)
void bucket_hist_kernel(const int* __restrict__ dst, int* __restrict__ btotal, int n) {
    __shared__ int lh[NBUK];
    const int tid = threadIdx.x;
    for (int i = tid; i < NBUK; i += 256) lh[i] = 0;
    __syncthreads();
    const int e0 = blockIdx.x * PCHUNK;
    const int e1 = min(e0 + PCHUNK, n);
    for (int i = e0 + tid; i < e1; i += 256)
        atomicAdd(&lh[dst[i] >> 8], 1);
    __syncthreads();
    for (int i = tid; i < NBUK; i += 256)
        if (lh[i]) atomicAdd(&btotal[i], lh[i]);
}

// One wave: exclusive scan of 196 bucket totals (4 per lane).
__global__ __launch_bounds__(64)
void bucket_scan_kernel(const int* __restrict__ btotal, int* __restrict__ bbase,
                        int* __restrict__ gcursor, int* __restrict__ offsets) {
    const int lane = threadIdx.x;
    int c[4];
    int s = 0;
    #pragma unroll
    for (int j = 0; j < 4; ++j) {
        int idx = lane * 4 + j;
        c[j] = (idx < NBUK) ? btotal[idx] : 0;
        s += c[j];
    }
    int v = s;
    #pragma unroll
    for (int o = 1; o < 64; o <<= 1) {
        int u = __shfl_up(v, o);
        if (lane >= o) v += u;
    }
    int run = v - s;   // exclusive
    #pragma unroll
    for (int j = 0; j < 4; ++j) {
        int idx = lane * 4 + j;
        if (idx < NBUK) { bbase[idx] = run; gcursor[idx] = run; }
        run += c[j];
    }
    if (lane == 63) {
        bbase[NBUK] = v;            // total edges
        offsets[N_NODES] = v;
    }
}

// Partition edges into buckets. Per-block LDS hist -> one reservation atomic
// per (block,bucket) -> scatter packed (local_dst<<16 | src). Each block's
// writes per bucket are a short contiguous run -> merge in the XCD L2.
__global__ __launch_bounds__(256)
void partition_kernel(const int* __restrict__ src, const int* __restrict__ dst,
                      int* __restrict__ gcursor, int* __restrict__ packed, int n) {
    __shared__ int lh[NBUK];
    __shared__ int lbase[NBUK];
    const int tid = threadIdx.x;
    const int e0 = blockIdx.x * PCHUNK;
    const int e1 = min(e0 + PCHUNK, n);
    for (int i = tid; i < NBUK; i += 256) lh[i] = 0;
    __syncthreads();
    for (int i = e0 + tid; i < e1; i += 256)
        atomicAdd(&lh[dst[i] >> 8], 1);
    __syncthreads();
    for (int i = tid; i < NBUK; i += 256) {
        int cnt = lh[i];
        lbase[i] = cnt ? atomicAdd(&gcursor[i], cnt) : 0;
    }
    __syncthreads();
    for (int i = tid; i < NBUK; i += 256) lh[i] = 0;   // reuse as local cursor
    __syncthreads();
    for (int i = e0 + tid; i < e1; i += 256) {
        int d = dst[i], s = src[i];
        int b = d >> 8;
        int r = atomicAdd(&lh[b], 1);
        packed[lbase[b] + r] = ((d & 255) << 16) | s;   // src < 50000 < 2^16
    }
}

// One block per bucket: exact CSR for its 256 nodes. All writes land in a
// contiguous ~16KB window owned by this block -> XCD-local, merges fine.
__global__ __launch_bounds__(256)
void csr_local_kernel(const int* __restrict__ packed, const int* __restrict__ bbase,
                      int* __restrict__ offsets, int* __restrict__ csr_src) {
    __shared__ int lh[256];
    __shared__ int loff[256];
    __shared__ int ws4[4];
    const int tid = threadIdx.x;
    const int lane = tid & 63;
    const int wv = tid >> 6;
    const int b = blockIdx.x;
    const int node0 = b * 256;
    const int ncnt = min(256, N_NODES - node0);
    const int lo = bbase[b], hi = bbase[b + 1];

    lh[tid] = 0;
    __syncthreads();
    for (int i = lo + tid; i < hi; i += 256)
        atomicAdd(&lh[packed[i] >> 16], 1);
    __syncthreads();
    int c = lh[tid];
    int v = c;
    #pragma unroll
    for (int o = 1; o < 64; o <<= 1) {
        int u = __shfl_up(v, o);
        if (lane >= o) v += u;
    }
    if (lane == 63) ws4[wv] = v;
    __syncthreads();
    if (tid == 0) {
        int r = 0;
        #pragma unroll
        for (int j = 0; j < 4; ++j) { int t = ws4[j]; ws4[j] = r; r += t; }
    }
    __syncthreads();
    int ex = ws4[wv] + (v - c);
    loff[tid] = ex;
    if (tid < ncnt) offsets[node0 + tid] = lo + ex;   // contiguous write
    lh[tid] = 0;                                      // reuse as rank cursor
    __syncthreads();
    for (int i = lo + tid; i < hi; i += 256) {
        int p = packed[i];
        int l = p >> 16;
        int r = atomicAdd(&lh[l], 1);
        csr_src[lo + loff[l] + r] = p & 0xFFFF;
    }
}

// ---- GEMM + aggregate (unchanged from round 4) -----------------------------

__global__ __launch_bounds__(256)
void convert_w_kernel(const float* __restrict__ Ws, const float* __restrict__ Wn,
                      const float* __restrict__ b_self, const float* __restrict__ bias,
                      __bf16* __restrict__ Ws16, __bf16* __restrict__ Wn16,
                      float* __restrict__ bias_comb) {
    if (blockIdx.x < 16) {
        int i = (blockIdx.x * 256 + threadIdx.x) * 4;
        float4 a = *(const float4*)(Ws + i);
        float4 b = *(const float4*)(Wn + i);
        bf16x4 s, n;
        s[0]=(__bf16)a.x; s[1]=(__bf16)a.y; s[2]=(__bf16)a.z; s[3]=(__bf16)a.w;
        n[0]=(__bf16)b.x; n[1]=(__bf16)b.y; n[2]=(__bf16)b.z; n[3]=(__bf16)b.w;
        *(bf16x4*)(Ws16 + i) = s;
        *(bf16x4*)(Wn16 + i) = n;
    } else if (threadIdx.x < D) {
        bias_comb[threadIdx.x] = b_self[threadIdx.x] + bias[threadIdx.x];
    }
}

__global__ __launch_bounds__(256)
void gemm_kernel(const float* __restrict__ feat,
                 const __bf16* __restrict__ Ws16,
                 const __bf16* __restrict__ Wn16,
                 const float* __restrict__ bias_comb,
                 float* __restrict__ out,
                 __bf16* __restrict__ g16) {
    const int tid  = threadIdx.x;
    const int wv   = tid >> 6;
    const int lane = tid & 63;
    const int m    = lane & 15;
    const int quad = lane >> 4;
    const int n0   = blockIdx.x * 32;
    const int kb   = quad * 8;

    f32x4 accS[2][2] = {};
    f32x4 accN[2][2] = {};

    #pragma unroll
    for (int k0 = 0; k0 < D; k0 += 32) {
        const int kbase = k0 + kb;
        bf16x8 a[2];
        #pragma unroll
        for (int rt = 0; rt < 2; ++rt) {
            int row = n0 + rt * 16 + m;
            row = row < N_NODES ? row : N_NODES - 1;
            const float* p = feat + (size_t)row * D + kbase;
            float4 f0 = *(const float4*)p;
            float4 f1 = *(const float4*)(p + 4);
            bf16x8 t;
            t[0]=(__bf16)f0.x; t[1]=(__bf16)f0.y; t[2]=(__bf16)f0.z; t[3]=(__bf16)f0.w;
            t[4]=(__bf16)f1.x; t[5]=(__bf16)f1.y; t[6]=(__bf16)f1.z; t[7]=(__bf16)f1.w;
            a[rt] = t;
        }
        #pragma unroll
        for (int ct = 0; ct < 2; ++ct) {
            int col = wv * 32 + ct * 16 + m;
            bf16x8 bs = *(const bf16x8*)(Ws16 + (size_t)col * D + kbase);
            bf16x8 bn = *(const bf16x8*)(Wn16 + (size_t)col * D + kbase);
            #pragma unroll
            for (int rt = 0; rt < 2; ++rt) {
                accS[rt][ct] = __builtin_amdgcn_mfma_f32_16x16x32_bf16(a[rt], bs, accS[rt][ct], 0, 0, 0);
                accN[rt][ct] = __builtin_amdgcn_mfma_f32_16x16x32_bf16(a[rt], bn, accN[rt][ct], 0, 0, 0);
            }
        }
    }

    #pragma unroll
    for (int ct = 0; ct < 2; ++ct) {
        int col = wv * 32 + ct * 16 + m;
        float bb = bias_comb[col];
        #pragma unroll
        for (int rt = 0; rt < 2; ++rt) {
            #pragma unroll
            for (int r = 0; r < 4; ++r) {
                int node = n0 + rt * 16 + quad * 4 + r;
                if (node < N_NODES) {
                    out[(size_t)node * D + col] = accS[rt][ct][r] + bb;
                    g16[(size_t)node * D + col] = (__bf16)accN[rt][ct][r];
                }
            }
        }
    }
}

__device__ __forceinline__ float bf2f(unsigned short u) {
    union { unsigned int i; float f; } c;
    c.i = (unsigned int)u << 16;
    return c.f;
}

__global__ __launch_bounds__(256)
void aggregate_g_kernel(const __bf16* __restrict__ g16,
                        const int* __restrict__ offsets,
                        const int* __restrict__ csr_src,
                        float* __restrict__ out) {
    int node = blockIdx.x * 8 + (threadIdx.x >> 5);
    if (node >= N_NODES) return;
    int lane = threadIdx.x & 31;
    int beg = offsets[node], end = offsets[node + 1];
    const unsigned short* g = (const unsigned short*)g16;
    float a0 = 0.f, a1 = 0.f, a2 = 0.f, a3 = 0.f;
    int i = beg;
    for (; i + 1 < end; i += 2) {
        int s0 = csr_src[i], s1 = csr_src[i + 1];
        ushort4 u0 = *(const ushort4*)(g + (size_t)s0 * D + lane * 4);
        ushort4 u1 = *(const ushort4*)(g + (size_t)s1 * D + lane * 4);
        a0 += bf2f(u0.x) + bf2f(u1.x);
        a1 += bf2f(u0.y) + bf2f(u1.y);
        a2 += bf2f(u0.z) + bf2f(u1.z);
        a3 += bf2f(u0.w) + bf2f(u1.w);
    }
    if (i < end) {
        ushort4 u0 = *(const ushort4*)(g + (size_t)csr_src[i] * D + lane * 4);
        a0 += bf2f(u0.x); a1 += bf2f(u0.y); a2 += bf2f(u0.z); a3 += bf2f(u0.w);
    }
    int dg = end - beg;
    float sc = dg > 0 ? 1.0f / (float)dg : 0.f;   // DGL mean: 0 for deg==0
    float4 o = *(float4*)(out + (size_t)node * D + lane * 4);
    o.x += a0 * sc; o.y += a1 * sc; o.z += a2 * sc; o.w += a3 * sc;
    *(float4*)(out + (size_t)node * D + lane * 4) = o;
}

extern "C" void kernel_launch(void* const* d_in, const int* in_sizes, int n_in,
                              void* d_out, int out_size, void* d_ws, size_t ws_size,
                              hipStream_t stream) {
    const float* feat    = (const float*)d_in[0];
    const int*   src     = (const int*)d_in[1];
    const int*   dst     = (const int*)d_in[2];
    const float* W_self  = (const float*)d_in[3];
    const float* b_self  = (const float*)d_in[4];
    const float* W_neigh = (const float*)d_in[5];
    const float* bias    = (const float*)d_in[6];
    float* out = (float*)d_out;
    char*  ws  = (char*)d_ws;

    int* offsets = (int*)(ws + OFF_OFFSETS);
    int* btotal  = (int*)(ws + OFF_BTOTAL);
    int* gcursor = (int*)(ws + OFF_GCURSOR);
    int* bbase   = (int*)(ws + OFF_BBASE);
    int* csr_src = (int*)(ws + OFF_CSR);
    int* packed  = (int*)(ws + OFF_PACKED);
    __bf16* g16  = (__bf16*)(ws + OFF_G16);
    __bf16* Ws16 = (__bf16*)(ws + OFF_WS16);
    __bf16* Wn16 = (__bf16*)(ws + OFF_WN16);
    float* biasc = (float*)(ws + OFF_BIASC);
    const int n_edges = in_sizes[1];

    hipMemsetAsync(btotal, 0, 256 * sizeof(int), stream);
    bucket_hist_kernel<<<dim3(PBLOCKS), 256, 0, stream>>>(dst, btotal, n_edges);
    bucket_scan_kernel<<<dim3(1), 64, 0, stream>>>(btotal, bbase, gcursor, offsets);
    partition_kernel<<<dim3(PBLOCKS), 256, 0, stream>>>(src, dst, gcursor, packed, n_edges);
    csr_local_kernel<<<dim3(NBUK), 256, 0, stream>>>(packed, bbase, offsets, csr_src);

    convert_w_kernel<<<dim3(17), 256, 0, stream>>>(W_self, W_neigh, b_self, bias,
                                                   Ws16, Wn16, biasc);
    gemm_kernel<<<dim3((N_NODES + 31) / 32), 256, 0, stream>>>(feat, Ws16, Wn16,
                                                               biasc, out, g16);
    aggregate_g_kernel<<<dim3((N_NODES + 7) / 8), 256, 0, stream>>>(g16, offsets,
                                                                    csr_src, out);
}